// Round 18
// baseline (122.118 us; speedup 1.0000x reference)
//
#include <hip/hip_runtime.h>

#define BB 1024
#define VV 6890
#define NJ 24
#define NBETA 10
#define PF 207            // (J-1)*9
#define V3 (VV*3)         // 20670
#define KP 224            // GEMM1 K: 207 pose + 10 shape + 2 vtemp(hi/lo) + 5 zero
#define VTB 64            // vertices per block tile in k_main
#define M3 (VTB*3)        // 192 v3-rows per tile
#define NVT ((VV + VTB - 1) / VTB)   // 108
#define V3PAD (NVT * VTB * 3)        // 20736 rows in pdT (row = v*3+c, interleaved)
#define VPAD (NVT * VTB)             // 6912
#define K2 32             // GEMM2 K: 24 joints + 1 transl-one + 7 zero
#define NCH 8             // jreg chunks
#define CHV 862           // ceil(VV/NCH)
#define NBLK_A (NVT * 4)             // 432: (v-block, k-quarter)
#define NBLK_B (VPAD / 256)          // 27
#define NBLK_C (NJ * NCH)            // 192
#define NBT 4             // batch-tiles per k_main block
#define XSW 52            // xls per-wave stride (u16): [batch][v3local], bf16
#define TSW 200           // Tls per-wave stride (u16): 400B, 8-B aligned

typedef float f32x4 __attribute__((ext_vector_type(4)));
typedef short s16x8 __attribute__((ext_vector_type(8)));
typedef short s16x4 __attribute__((ext_vector_type(4)));

__device__ __constant__ int kParents[NJ] = {-1,0,0,0,1,2,3,4,5,6,7,8,9,9,9,12,13,14,16,17,18,19,20,21};
// tree depth level of each joint (root = 0)
__device__ __constant__ int kLevel[NJ]   = {0,1,1,1,2,2,2,3,3,3,4,4,4,4,4,5,5,5,6,6,7,7,8,8};

__device__ __forceinline__ unsigned short f2bf(float x) {
    unsigned int u = __float_as_uint(x);
    unsigned int r = (u + 0x7fffu + ((u >> 16) & 1u)) >> 16;
    return (unsigned short)r;
}
__device__ __forceinline__ float bf2f(unsigned short h) {
    return __uint_as_float((unsigned int)h << 16);
}

// ---------------------------------------------------------------------------
// k_prep_all (byte-identical to R16): A = pdT interleaved transpose,
// B = lbswB, C = jreg partials (float2 sdirs loads).
// ---------------------------------------------------------------------------
__global__ __launch_bounds__(256) void k_prep_all(
    const float* __restrict__ pdirs,     // (207, V3)
    const float* __restrict__ sdirs,     // (V3, 10)
    const float* __restrict__ vtemp,     // (V3)
    const float* __restrict__ lbsw,      // (V, 24)
    const float* __restrict__ Jreg,      // (24, V)
    unsigned short* __restrict__ pdT,    // (V3PAD, KP) interleaved
    unsigned short* __restrict__ lbswB,  // (VPAD, K2)
    float* __restrict__ jpart)           // (24, NCH, 33)
{
    int bid = blockIdx.x;
    int t = threadIdx.x;

    if (bid < NBLK_A) {
        int vb = bid >> 2;              // v-block 0..107
        int kq = bid & 3;               // k-quarter 0..3
        int kc0 = kq * 56;
        int v0 = vb * 64;
        __shared__ unsigned short tileA[3][56][65];   // 21840 B

        int ksub = t >> 6;              // 0..3
        int vo   = t & 63;
        int v    = v0 + vo;
        bool valid = v < VV;
        int v3b  = v * 3;
#pragma unroll
        for (int i = 0; i < 14; ++i) {
            int kl = ksub * 14 + i;     // 0..55
            int k  = kc0 + kl;
            float c0 = 0.f, c1 = 0.f, c2 = 0.f;
            if (valid) {
                if (k < PF) {
                    const float* p = pdirs + (size_t)k * V3 + v3b;
                    c0 = p[0]; c1 = p[1]; c2 = p[2];
                } else if (k < PF + NBETA) {
                    int l = k - PF;
                    c0 = sdirs[(size_t)(v3b + 0) * NBETA + l];
                    c1 = sdirs[(size_t)(v3b + 1) * NBETA + l];
                    c2 = sdirs[(size_t)(v3b + 2) * NBETA + l];
                } else if (k == PF + NBETA) {
                    c0 = vtemp[v3b]; c1 = vtemp[v3b + 1]; c2 = vtemp[v3b + 2];
                } else if (k == PF + NBETA + 1) {
                    float x0 = vtemp[v3b], x1 = vtemp[v3b + 1], x2 = vtemp[v3b + 2];
                    c0 = x0 - bf2f(f2bf(x0));
                    c1 = x1 - bf2f(f2bf(x1));
                    c2 = x2 - bf2f(f2bf(x2));
                }
            }
            tileA[0][kl][vo] = f2bf(c0);
            tileA[1][kl][vo] = f2bf(c1);
            tileA[2][kl][vo] = f2bf(c2);
        }
        __syncthreads();

        int vo2 = t >> 2;               // 0..63
        int sub = t & 3;
#pragma unroll
        for (int c = 0; c < 3; ++c) {
#pragma unroll
            for (int j = 0; j < 2; ++j) {
                int ch = sub + 4 * j;   // 0..7, need 0..6
                if (ch < 7) {
                    union { s16x8 v8; unsigned short u[8]; } pk;
#pragma unroll
                    for (int i = 0; i < 8; ++i) pk.u[i] = tileA[c][ch * 8 + i][vo2];
                    *(s16x8*)(pdT + (size_t)((v0 + vo2) * 3 + c) * KP
                                   + kc0 + ch * 8) = pk.v8;
                }
            }
        }
    } else if (bid < NBLK_A + NBLK_B) {
        int v = (bid - NBLK_A) * 256 + t;
        bool valid = v < VV;
        unsigned short* o = lbswB + (size_t)v * K2;
        union { s16x8 v8; unsigned short u[8]; } pk;
#pragma unroll
        for (int g = 0; g < 3; ++g) {
#pragma unroll
            for (int i = 0; i < 8; ++i)
                pk.u[i] = valid ? f2bf(lbsw[(size_t)v * NJ + g * 8 + i]) : (unsigned short)0;
            *(s16x8*)(o + g * 8) = pk.v8;
        }
        pk.u[0] = 0x3F80;               // col 24 = 1.0 (transl K-column)
#pragma unroll
        for (int i = 1; i < 8; ++i) pk.u[i] = 0;
        *(s16x8*)(o + 24) = pk.v8;
    } else {
        int idx = bid - NBLK_A - NBLK_B;
        int j  = idx / NCH;
        int ch = idx % NCH;
        int v0 = ch * CHV;
        int vend = min(VV, v0 + CHV);

        float acc[33];
#pragma unroll
        for (int i = 0; i < 33; ++i) acc[i] = 0.f;

        for (int v = v0 + t; v < vend; v += 256) {
            float w = Jreg[(size_t)j * VV + v];
            const float* sv = sdirs + (size_t)v * 30;
            float sd[30];
#pragma unroll
            for (int i = 0; i < 30; i += 2) {
                float2 x2 = *(const float2*)(sv + i);
                sd[i] = x2.x; sd[i + 1] = x2.y;
            }
#pragma unroll
            for (int c = 0; c < 3; ++c) {
                acc[30 + c] += w * vtemp[v * 3 + c];
#pragma unroll
                for (int l = 0; l < NBETA; ++l)
                    acc[c * NBETA + l] += w * sd[c * NBETA + l];
            }
        }
#pragma unroll
        for (int i = 0; i < 33; ++i) {
            float x = acc[i];
            for (int off = 32; off > 0; off >>= 1) x += __shfl_down(x, off);
            acc[i] = x;
        }
        __shared__ float sred[33][4];
        int wave = t >> 6, lane = t & 63;
        if (lane == 0) {
#pragma unroll
            for (int i = 0; i < 33; ++i) sred[i][wave] = acc[i];
        }
        __syncthreads();
        if (t == 0) {
#pragma unroll
            for (int i = 0; i < 33; ++i)
                jpart[(size_t)(j * NCH + ch) * 33 + i] =
                    sred[i][0] + sred[i][1] + sred[i][2] + sred[i][3];
        }
    }
}

// ---------------------------------------------------------------------------
// k_batch v2 (byte-identical to R16): one wave per batch, shfl chain.
// ---------------------------------------------------------------------------
__global__ __launch_bounds__(64) void k_batch(
    const float* __restrict__ transl,
    const float* __restrict__ orient,
    const float* __restrict__ betas,
    const float* __restrict__ bpose,
    const float* __restrict__ jpart,     // (24, NCH, 33)
    unsigned short* __restrict__ pfB,    // (B, KP)
    unsigned short* __restrict__ relBT,  // (B*12, K2)
    float* __restrict__ joints_out)      // (B, 24, 3)
{
    int b = blockIdx.x;
    int j = threadIdx.x;                 // lane; joints on 0..23

    __shared__ float sJ[NJ * 33];
    for (int idx = j; idx < NJ * 33; idx += 64) {
        int jj = idx / 33, i = idx % 33;
        float s = 0.f;
#pragma unroll
        for (int c = 0; c < NCH; ++c) s += jpart[(size_t)(jj * NCH + c) * 33 + i];
        sJ[idx] = s;
    }
    __syncthreads();

    float tr0 = transl[b * 3 + 0], tr1 = transl[b * 3 + 1], tr2 = transl[b * 3 + 2];

    float bet[NBETA];
#pragma unroll
    for (int l = 0; l < NBETA; ++l) bet[l] = betas[b * NBETA + l];

    bool act = j < NJ;
    int p   = (act && j > 0) ? kParents[j] : 0;
    int lvl = act ? kLevel[j] : 0;

    float jxx = 0.f, jyy = 0.f, jzz = 0.f;
    if (act) {
        jxx = sJ[j * 33 + 30]; jyy = sJ[j * 33 + 31]; jzz = sJ[j * 33 + 32];
#pragma unroll
        for (int l = 0; l < NBETA; ++l) {
            jxx += sJ[j * 33 + l]      * bet[l];
            jyy += sJ[j * 33 + 10 + l] * bet[l];
            jzz += sJ[j * 33 + 20 + l] * bet[l];
        }
    }
    float pxx = __shfl(jxx, p), pyy = __shfl(jyy, p), pzz = __shfl(jzz, p);

    float rx = 0.f, ry = 0.f, rz = 0.f;
    if (act) {
        if (j == 0) {
            rx = orient[b * 3 + 0]; ry = orient[b * 3 + 1]; rz = orient[b * 3 + 2];
        } else {
            rx = bpose[b * 69 + (j - 1) * 3 + 0];
            ry = bpose[b * 69 + (j - 1) * 3 + 1];
            rz = bpose[b * 69 + (j - 1) * 3 + 2];
        }
    }
    float ax = rx + 1e-8f, ay = ry + 1e-8f, az = rz + 1e-8f;
    float angle = sqrtf(ax * ax + ay * ay + az * az);
    float inv = 1.f / angle;
    float kx = rx * inv, ky = ry * inv, kz = rz * inv;
    float s = sinf(angle), c = cosf(angle), omc = 1.f - c;
    float R[9];
    R[0] = 1.f - omc * (ky * ky + kz * kz);
    R[1] = -s * kz + omc * (kx * ky);
    R[2] =  s * ky + omc * (kx * kz);
    R[3] =  s * kz + omc * (kx * ky);
    R[4] = 1.f - omc * (kx * kx + kz * kz);
    R[5] = -s * kx + omc * (ky * kz);
    R[6] = -s * ky + omc * (kx * kz);
    R[7] =  s * kx + omc * (ky * kz);
    R[8] = 1.f - omc * (kx * kx + ky * ky);

    if (act && j > 0) {
#pragma unroll
        for (int e = 0; e < 9; ++e) {
            float val = R[e] - ((e == 0 || e == 4 || e == 8) ? 1.f : 0.f);
            pfB[(size_t)b * KP + (j - 1) * 9 + e] = f2bf(val);
        }
    }

    float tx, ty, tz;
    if (j == 0) { tx = jxx; ty = jyy; tz = jzz; }
    else        { tx = jxx - pxx; ty = jyy - pyy; tz = jzz - pzz; }

    float C[12];
    C[0] = R[0]; C[1] = R[1]; C[2]  = R[2]; C[3]  = tx;
    C[4] = R[3]; C[5] = R[4]; C[6]  = R[5]; C[7]  = ty;
    C[8] = R[6]; C[9] = R[7]; C[10] = R[8]; C[11] = tz;

#pragma unroll
    for (int L = 1; L <= 8; ++L) {
        float P[12];
#pragma unroll
        for (int e = 0; e < 12; ++e) P[e] = __shfl(C[e], p);
        if (lvl == L) {
            float N[12];
#pragma unroll
            for (int r = 0; r < 3; ++r) {
#pragma unroll
                for (int cc = 0; cc < 3; ++cc)
                    N[r * 4 + cc] = P[r * 4 + 0] * R[0 * 3 + cc] +
                                    P[r * 4 + 1] * R[1 * 3 + cc] +
                                    P[r * 4 + 2] * R[2 * 3 + cc];
                N[r * 4 + 3] = P[r * 4 + 0] * tx + P[r * 4 + 1] * ty +
                               P[r * 4 + 2] * tz + P[r * 4 + 3];
            }
#pragma unroll
            for (int e = 0; e < 12; ++e) C[e] = N[e];
        }
    }

    if (act) {
        joints_out[(b * NJ + j) * 3 + 0] = C[3]  + tr0;
        joints_out[(b * NJ + j) * 3 + 1] = C[7]  + tr1;
        joints_out[(b * NJ + j) * 3 + 2] = C[11] + tr2;

        float bx = C[0] * jxx + C[1] * jyy + C[2]  * jzz;
        float by = C[4] * jxx + C[5] * jyy + C[6]  * jzz;
        float bz = C[8] * jxx + C[9] * jyy + C[10] * jzz;
        float relv[12];
        relv[0] = C[0]; relv[1] = C[1]; relv[2]  = C[2];  relv[3]  = C[3]  - bx;
        relv[4] = C[4]; relv[5] = C[5]; relv[6]  = C[6];  relv[7]  = C[7]  - by;
        relv[8] = C[8]; relv[9] = C[9]; relv[10] = C[10]; relv[11] = C[11] - bz;
#pragma unroll
        for (int e = 0; e < 12; ++e)
            relBT[(size_t)(b * 12 + e) * K2 + j] = f2bf(relv[e]);
    }

    for (int idx = j; idx < KP - PF; idx += 64) {
        float val = (idx < NBETA) ? bet[idx] : (idx < NBETA + 2 ? 1.0f : 0.f);
        pfB[(size_t)b * KP + PF + idx] = f2bf(val);
    }

    for (int idx = j; idx < 12 * 8; idx += 64) {
        int e = idx >> 3, col = 24 + (idx & 7);
        float val = 0.f;
        if (col == 24) val = (e == 3) ? tr0 : (e == 7) ? tr1 : (e == 11) ? tr2 : 0.f;
        relBT[(size_t)(b * 12 + e) * K2 + col] = f2bf(val);
    }
}

// ---------------------------------------------------------------------------
// k_main v12 = R16/R13 body with bf16 xls: LDS 38912 -> 32256 B, raising the
// occupancy cap from 4 to 5 blocks/CU (163840/32256 = 5.08). x stored as
// bf16 (error ~0.01 << 0.136 budget). Writes 8B-aligned s16x4 (2-way = free);
// epilogue x-read = 3x ds_read_u16 (bank-spread, no conflicts).
// ---------------------------------------------------------------------------
__global__ __launch_bounds__(256, 5) void k_main(
    const unsigned short* __restrict__ pdT,    // (V3PAD, KP) interleaved
    const unsigned short* __restrict__ pfB,    // (BB, KP)
    const unsigned short* __restrict__ lbswB,  // (VPAD, K2)
    const unsigned short* __restrict__ relBT,  // (BB*12, K2)
    float* __restrict__ verts)                 // (B,V,3)
{
    int btg = blockIdx.x;           // 0..15 (4 batch-tiles each)
    int vt  = blockIdx.y;           // 0..107
    int t   = threadIdx.x;
    int lane = t & 63;
    int w    = t >> 6;

    __shared__ unsigned short xls[4][16 * XSW];   // 6656 B  (bf16 x)
    __shared__ unsigned short Tls[4][16 * TSW];   // 25600 B

    int lr  = lane & 15;
    int hi2 = lane >> 4;
    int lk  = hi2 * 8;

    unsigned short* xw = &xls[w][0];
    unsigned short* Tw = &Tls[w][0];

    const unsigned short* pa = pdT + (size_t)(vt * M3 + w * 48 + lr) * KP + lk;
    s16x8 lf = *(const s16x8*)(lbswB + (size_t)(vt * VTB + w * 16 + lr) * K2 + lk);

    int vglob = vt * VTB + w * 16 + lr;
    bool vok = vglob < VV;

    for (int it = 0; it < NBT; ++it) {
        int b0 = (btg * NBT + it) * 16;

        // ---- GEMM1: D row = v3-sub (s*16+hi2*4+r), col = batch (lr) ----
        {
            f32x4 acc[3];
#pragma unroll
            for (int s = 0; s < 3; ++s) acc[s] = (f32x4){0.f,0.f,0.f,0.f};
            const unsigned short* pb = pfB + (size_t)(b0 + lr) * KP + lk;
#pragma unroll
            for (int ks = 0; ks < KP / 32; ++ks) {
                s16x8 bf = *(const s16x8*)(pb + ks * 32);
                s16x8 a0 = *(const s16x8*)(pa + ks * 32);
                s16x8 a1 = *(const s16x8*)(pa + (size_t)16 * KP + ks * 32);
                s16x8 a2 = *(const s16x8*)(pa + (size_t)32 * KP + ks * 32);
                acc[0] = __builtin_amdgcn_mfma_f32_16x16x32_bf16(a0, bf, acc[0], 0, 0, 0);
                acc[1] = __builtin_amdgcn_mfma_f32_16x16x32_bf16(a1, bf, acc[1], 0, 0, 0);
                acc[2] = __builtin_amdgcn_mfma_f32_16x16x32_bf16(a2, bf, acc[2], 0, 0, 0);
            }
            // xls[batch(lr)][v3local(s*16+hi2*4+r)] as bf16, s16x4 writes
#pragma unroll
            for (int s = 0; s < 3; ++s) {
                union { s16x4 v4; unsigned short u[4]; } px;
#pragma unroll
                for (int r = 0; r < 4; ++r) px.u[r] = f2bf(acc[s][r]);
                *(s16x4*)&xw[lr * XSW + s * 16 + hi2 * 4] = px.v4;
            }
        }

        // ---- GEMM2: T[be][vert] -> Tw[vert=lr][be] (per-wave, aligned) ----
#pragma unroll
        for (int mt = 0; mt < 12; ++mt) {
            s16x8 rf = *(const s16x8*)(relBT +
                (size_t)(b0 * 12 + mt * 16 + lr) * K2 + lk);
            f32x4 a2v = {0.f,0.f,0.f,0.f};
            a2v = __builtin_amdgcn_mfma_f32_16x16x32_bf16(rf, lf, a2v, 0, 0, 0);
            union { s16x4 v4; unsigned short u[4]; } pk;
#pragma unroll
            for (int r = 0; r < 4; ++r) pk.u[r] = f2bf(a2v[r]);
            *(s16x4*)&Tw[lr * TSW + mt * 16 + hi2 * 4] = pk.v4;
        }

        // ---- epilogue: vertex w*16+lr, batches hi2+4q ----
        if (vok) {
#pragma unroll
            for (int q = 0; q < 4; ++q) {
                int bl = hi2 + 4 * q;

                const unsigned short* xp = &xw[bl * XSW + 3 * lr];
                float x0 = bf2f(xp[0]);
                float x1 = bf2f(xp[1]);
                float x2 = bf2f(xp[2]);

                const unsigned short* tp = Tw + lr * TSW + bl * 12;
                uint2 dA = *(const uint2*)tp;
                uint2 dB = *(const uint2*)(tp + 4);
                uint2 dC = *(const uint2*)(tp + 8);
                float T0  = __uint_as_float(dA.x << 16);
                float T1  = __uint_as_float(dA.x & 0xffff0000u);
                float T2  = __uint_as_float(dA.y << 16);
                float T3  = __uint_as_float(dA.y & 0xffff0000u);
                float T4  = __uint_as_float(dB.x << 16);
                float T5  = __uint_as_float(dB.x & 0xffff0000u);
                float T6  = __uint_as_float(dB.y << 16);
                float T7  = __uint_as_float(dB.y & 0xffff0000u);
                float T8  = __uint_as_float(dC.x << 16);
                float T9  = __uint_as_float(dC.x & 0xffff0000u);
                float T10 = __uint_as_float(dC.y << 16);
                float T11 = __uint_as_float(dC.y & 0xffff0000u);

                float o0 = T0 * x0 + T1 * x1 + T2  * x2 + T3;
                float o1 = T4 * x0 + T5 * x1 + T6  * x2 + T7;
                float o2 = T8 * x0 + T9 * x1 + T10 * x2 + T11;

                float* o = verts + ((size_t)(b0 + bl) * VV + vglob) * 3;
                o[0] = o0; o[1] = o1; o[2] = o2;
            }
        }
    }
}

extern "C" void kernel_launch(void* const* d_in, const int* in_sizes, int n_in,
                              void* d_out, int out_size, void* d_ws, size_t ws_size,
                              hipStream_t stream) {
    const float* transl = (const float*)d_in[0];
    const float* orient = (const float*)d_in[1];
    const float* betas  = (const float*)d_in[2];
    const float* bpose  = (const float*)d_in[3];
    const float* vtemp  = (const float*)d_in[4];
    const float* sdirs  = (const float*)d_in[5];
    const float* pdirs  = (const float*)d_in[6];
    const float* jreg   = (const float*)d_in[7];
    const float* lbsw   = (const float*)d_in[8];

    float* out = (float*)d_out;
    float* verts_out  = out;
    float* joints_out = out + (size_t)BB * VV * 3;

    float* ws    = (float*)d_ws;
    float* jpart = ws;                                   // 24*8*33 = 6336 f
    unsigned short* pfB   = (unsigned short*)(ws + 6336);      // B*KP
    unsigned short* pdT   = pfB + (size_t)BB * KP;             // V3PAD*KP
    unsigned short* lbswB = pdT + (size_t)V3PAD * KP;          // VPAD*K2
    unsigned short* relBT = lbswB + (size_t)VPAD * K2;         // B*12*K2

    k_prep_all<<<NBLK_A + NBLK_B + NBLK_C, 256, 0, stream>>>(
        pdirs, sdirs, vtemp, lbsw, jreg, pdT, lbswB, jpart);
    k_batch<<<BB, 64, 0, stream>>>(transl, orient, betas, bpose,
                                   jpart, pfB, relBT, joints_out);
    dim3 g(BB / 16 / NBT, NVT);
    k_main<<<g, 256, 0, stream>>>(pdT, pfB, lbswB, relBT, verts_out);
}

// Round 19
// 99.496 us; speedup vs baseline: 1.2274x; 1.2274x over previous
//
#include <hip/hip_runtime.h>

#define BB 1024
#define VV 6890
#define NJ 24
#define NBETA 10
#define PF 207            // (J-1)*9
#define V3 (VV*3)         // 20670
#define KP 224            // GEMM1 K: 207 pose + 10 shape + 2 vtemp(hi/lo) + 5 zero
#define VTB 64            // vertices per block tile in k_main
#define M3 (VTB*3)        // 192 v3-rows per tile
#define NVT ((VV + VTB - 1) / VTB)   // 108
#define V3PAD (NVT * VTB * 3)        // 20736 rows in pdT (row = v*3+c, interleaved)
#define VPAD (NVT * VTB)             // 6912
#define K2 32             // GEMM2 K: 24 joints + 1 transl-one + 7 zero
#define NCH 8             // jreg chunks
#define CHV 862           // ceil(VV/NCH)
#define NBLK_A (NVT * 4)             // 432: (v-block, k-quarter)
#define NBLK_B (VPAD / 256)          // 27
#define NBLK_C (NJ * NCH)            // 192
#define NBT 4             // batch-tiles per k_main block
#define XSW 52            // xls per-wave stride (dwords): [batch][v3local]
#define TSW 200           // Tls per-wave stride (u16): 400B, 8-B aligned
#define NWG (16 * NVT)    // 1728 k_main workgroups (1728 % 8 == 0 -> bijective)

typedef float f32x4 __attribute__((ext_vector_type(4)));
typedef short s16x8 __attribute__((ext_vector_type(8)));
typedef short s16x4 __attribute__((ext_vector_type(4)));

__device__ __constant__ int kParents[NJ] = {-1,0,0,0,1,2,3,4,5,6,7,8,9,9,9,12,13,14,16,17,18,19,20,21};
// tree depth level of each joint (root = 0)
__device__ __constant__ int kLevel[NJ]   = {0,1,1,1,2,2,2,3,3,3,4,4,4,4,4,5,5,5,6,6,7,7,8,8};

__device__ __forceinline__ unsigned short f2bf(float x) {
    unsigned int u = __float_as_uint(x);
    unsigned int r = (u + 0x7fffu + ((u >> 16) & 1u)) >> 16;
    return (unsigned short)r;
}
__device__ __forceinline__ float bf2f(unsigned short h) {
    return __uint_as_float((unsigned int)h << 16);
}

// ---------------------------------------------------------------------------
// k_prep_all (byte-identical to R16): A = pdT interleaved transpose,
// B = lbswB, C = jreg partials (float2 sdirs loads).
// ---------------------------------------------------------------------------
__global__ __launch_bounds__(256) void k_prep_all(
    const float* __restrict__ pdirs,     // (207, V3)
    const float* __restrict__ sdirs,     // (V3, 10)
    const float* __restrict__ vtemp,     // (V3)
    const float* __restrict__ lbsw,      // (V, 24)
    const float* __restrict__ Jreg,      // (24, V)
    unsigned short* __restrict__ pdT,    // (V3PAD, KP) interleaved
    unsigned short* __restrict__ lbswB,  // (VPAD, K2)
    float* __restrict__ jpart)           // (24, NCH, 33)
{
    int bid = blockIdx.x;
    int t = threadIdx.x;

    if (bid < NBLK_A) {
        int vb = bid >> 2;              // v-block 0..107
        int kq = bid & 3;               // k-quarter 0..3
        int kc0 = kq * 56;
        int v0 = vb * 64;
        __shared__ unsigned short tileA[3][56][65];   // 21840 B

        int ksub = t >> 6;              // 0..3
        int vo   = t & 63;
        int v    = v0 + vo;
        bool valid = v < VV;
        int v3b  = v * 3;
#pragma unroll
        for (int i = 0; i < 14; ++i) {
            int kl = ksub * 14 + i;     // 0..55
            int k  = kc0 + kl;
            float c0 = 0.f, c1 = 0.f, c2 = 0.f;
            if (valid) {
                if (k < PF) {
                    const float* p = pdirs + (size_t)k * V3 + v3b;
                    c0 = p[0]; c1 = p[1]; c2 = p[2];
                } else if (k < PF + NBETA) {
                    int l = k - PF;
                    c0 = sdirs[(size_t)(v3b + 0) * NBETA + l];
                    c1 = sdirs[(size_t)(v3b + 1) * NBETA + l];
                    c2 = sdirs[(size_t)(v3b + 2) * NBETA + l];
                } else if (k == PF + NBETA) {
                    c0 = vtemp[v3b]; c1 = vtemp[v3b + 1]; c2 = vtemp[v3b + 2];
                } else if (k == PF + NBETA + 1) {
                    float x0 = vtemp[v3b], x1 = vtemp[v3b + 1], x2 = vtemp[v3b + 2];
                    c0 = x0 - bf2f(f2bf(x0));
                    c1 = x1 - bf2f(f2bf(x1));
                    c2 = x2 - bf2f(f2bf(x2));
                }
            }
            tileA[0][kl][vo] = f2bf(c0);
            tileA[1][kl][vo] = f2bf(c1);
            tileA[2][kl][vo] = f2bf(c2);
        }
        __syncthreads();

        int vo2 = t >> 2;               // 0..63
        int sub = t & 3;
#pragma unroll
        for (int c = 0; c < 3; ++c) {
#pragma unroll
            for (int j = 0; j < 2; ++j) {
                int ch = sub + 4 * j;   // 0..7, need 0..6
                if (ch < 7) {
                    union { s16x8 v8; unsigned short u[8]; } pk;
#pragma unroll
                    for (int i = 0; i < 8; ++i) pk.u[i] = tileA[c][ch * 8 + i][vo2];
                    *(s16x8*)(pdT + (size_t)((v0 + vo2) * 3 + c) * KP
                                   + kc0 + ch * 8) = pk.v8;
                }
            }
        }
    } else if (bid < NBLK_A + NBLK_B) {
        int v = (bid - NBLK_A) * 256 + t;
        bool valid = v < VV;
        unsigned short* o = lbswB + (size_t)v * K2;
        union { s16x8 v8; unsigned short u[8]; } pk;
#pragma unroll
        for (int g = 0; g < 3; ++g) {
#pragma unroll
            for (int i = 0; i < 8; ++i)
                pk.u[i] = valid ? f2bf(lbsw[(size_t)v * NJ + g * 8 + i]) : (unsigned short)0;
            *(s16x8*)(o + g * 8) = pk.v8;
        }
        pk.u[0] = 0x3F80;               // col 24 = 1.0 (transl K-column)
#pragma unroll
        for (int i = 1; i < 8; ++i) pk.u[i] = 0;
        *(s16x8*)(o + 24) = pk.v8;
    } else {
        int idx = bid - NBLK_A - NBLK_B;
        int j  = idx / NCH;
        int ch = idx % NCH;
        int v0 = ch * CHV;
        int vend = min(VV, v0 + CHV);

        float acc[33];
#pragma unroll
        for (int i = 0; i < 33; ++i) acc[i] = 0.f;

        for (int v = v0 + t; v < vend; v += 256) {
            float w = Jreg[(size_t)j * VV + v];
            const float* sv = sdirs + (size_t)v * 30;
            float sd[30];
#pragma unroll
            for (int i = 0; i < 30; i += 2) {
                float2 x2 = *(const float2*)(sv + i);
                sd[i] = x2.x; sd[i + 1] = x2.y;
            }
#pragma unroll
            for (int c = 0; c < 3; ++c) {
                acc[30 + c] += w * vtemp[v * 3 + c];
#pragma unroll
                for (int l = 0; l < NBETA; ++l)
                    acc[c * NBETA + l] += w * sd[c * NBETA + l];
            }
        }
#pragma unroll
        for (int i = 0; i < 33; ++i) {
            float x = acc[i];
            for (int off = 32; off > 0; off >>= 1) x += __shfl_down(x, off);
            acc[i] = x;
        }
        __shared__ float sred[33][4];
        int wave = t >> 6, lane = t & 63;
        if (lane == 0) {
#pragma unroll
            for (int i = 0; i < 33; ++i) sred[i][wave] = acc[i];
        }
        __syncthreads();
        if (t == 0) {
#pragma unroll
            for (int i = 0; i < 33; ++i)
                jpart[(size_t)(j * NCH + ch) * 33 + i] =
                    sred[i][0] + sred[i][1] + sred[i][2] + sred[i][3];
        }
    }
}

// ---------------------------------------------------------------------------
// k_batch v2 (byte-identical to R16): one wave per batch, shfl chain.
// ---------------------------------------------------------------------------
__global__ __launch_bounds__(64) void k_batch(
    const float* __restrict__ transl,
    const float* __restrict__ orient,
    const float* __restrict__ betas,
    const float* __restrict__ bpose,
    const float* __restrict__ jpart,     // (24, NCH, 33)
    unsigned short* __restrict__ pfB,    // (B, KP)
    unsigned short* __restrict__ relBT,  // (B*12, K2)
    float* __restrict__ joints_out)      // (B, 24, 3)
{
    int b = blockIdx.x;
    int j = threadIdx.x;                 // lane; joints on 0..23

    __shared__ float sJ[NJ * 33];
    for (int idx = j; idx < NJ * 33; idx += 64) {
        int jj = idx / 33, i = idx % 33;
        float s = 0.f;
#pragma unroll
        for (int c = 0; c < NCH; ++c) s += jpart[(size_t)(jj * NCH + c) * 33 + i];
        sJ[idx] = s;
    }
    __syncthreads();

    float tr0 = transl[b * 3 + 0], tr1 = transl[b * 3 + 1], tr2 = transl[b * 3 + 2];

    float bet[NBETA];
#pragma unroll
    for (int l = 0; l < NBETA; ++l) bet[l] = betas[b * NBETA + l];

    bool act = j < NJ;
    int p   = (act && j > 0) ? kParents[j] : 0;
    int lvl = act ? kLevel[j] : 0;

    float jxx = 0.f, jyy = 0.f, jzz = 0.f;
    if (act) {
        jxx = sJ[j * 33 + 30]; jyy = sJ[j * 33 + 31]; jzz = sJ[j * 33 + 32];
#pragma unroll
        for (int l = 0; l < NBETA; ++l) {
            jxx += sJ[j * 33 + l]      * bet[l];
            jyy += sJ[j * 33 + 10 + l] * bet[l];
            jzz += sJ[j * 33 + 20 + l] * bet[l];
        }
    }
    float pxx = __shfl(jxx, p), pyy = __shfl(jyy, p), pzz = __shfl(jzz, p);

    float rx = 0.f, ry = 0.f, rz = 0.f;
    if (act) {
        if (j == 0) {
            rx = orient[b * 3 + 0]; ry = orient[b * 3 + 1]; rz = orient[b * 3 + 2];
        } else {
            rx = bpose[b * 69 + (j - 1) * 3 + 0];
            ry = bpose[b * 69 + (j - 1) * 3 + 1];
            rz = bpose[b * 69 + (j - 1) * 3 + 2];
        }
    }
    float ax = rx + 1e-8f, ay = ry + 1e-8f, az = rz + 1e-8f;
    float angle = sqrtf(ax * ax + ay * ay + az * az);
    float inv = 1.f / angle;
    float kx = rx * inv, ky = ry * inv, kz = rz * inv;
    float s = sinf(angle), c = cosf(angle), omc = 1.f - c;
    float R[9];
    R[0] = 1.f - omc * (ky * ky + kz * kz);
    R[1] = -s * kz + omc * (kx * ky);
    R[2] =  s * ky + omc * (kx * kz);
    R[3] =  s * kz + omc * (kx * ky);
    R[4] = 1.f - omc * (kx * kx + kz * kz);
    R[5] = -s * kx + omc * (ky * kz);
    R[6] = -s * ky + omc * (kx * kz);
    R[7] =  s * kx + omc * (ky * kz);
    R[8] = 1.f - omc * (kx * kx + ky * ky);

    if (act && j > 0) {
#pragma unroll
        for (int e = 0; e < 9; ++e) {
            float val = R[e] - ((e == 0 || e == 4 || e == 8) ? 1.f : 0.f);
            pfB[(size_t)b * KP + (j - 1) * 9 + e] = f2bf(val);
        }
    }

    float tx, ty, tz;
    if (j == 0) { tx = jxx; ty = jyy; tz = jzz; }
    else        { tx = jxx - pxx; ty = jyy - pyy; tz = jzz - pzz; }

    float C[12];
    C[0] = R[0]; C[1] = R[1]; C[2]  = R[2]; C[3]  = tx;
    C[4] = R[3]; C[5] = R[4]; C[6]  = R[5]; C[7]  = ty;
    C[8] = R[6]; C[9] = R[7]; C[10] = R[8]; C[11] = tz;

#pragma unroll
    for (int L = 1; L <= 8; ++L) {
        float P[12];
#pragma unroll
        for (int e = 0; e < 12; ++e) P[e] = __shfl(C[e], p);
        if (lvl == L) {
            float N[12];
#pragma unroll
            for (int r = 0; r < 3; ++r) {
#pragma unroll
                for (int cc = 0; cc < 3; ++cc)
                    N[r * 4 + cc] = P[r * 4 + 0] * R[0 * 3 + cc] +
                                    P[r * 4 + 1] * R[1 * 3 + cc] +
                                    P[r * 4 + 2] * R[2 * 3 + cc];
                N[r * 4 + 3] = P[r * 4 + 0] * tx + P[r * 4 + 1] * ty +
                               P[r * 4 + 2] * tz + P[r * 4 + 3];
            }
#pragma unroll
            for (int e = 0; e < 12; ++e) C[e] = N[e];
        }
    }

    if (act) {
        joints_out[(b * NJ + j) * 3 + 0] = C[3]  + tr0;
        joints_out[(b * NJ + j) * 3 + 1] = C[7]  + tr1;
        joints_out[(b * NJ + j) * 3 + 2] = C[11] + tr2;

        float bx = C[0] * jxx + C[1] * jyy + C[2]  * jzz;
        float by = C[4] * jxx + C[5] * jyy + C[6]  * jzz;
        float bz = C[8] * jxx + C[9] * jyy + C[10] * jzz;
        float relv[12];
        relv[0] = C[0]; relv[1] = C[1]; relv[2]  = C[2];  relv[3]  = C[3]  - bx;
        relv[4] = C[4]; relv[5] = C[5]; relv[6]  = C[6];  relv[7]  = C[7]  - by;
        relv[8] = C[8]; relv[9] = C[9]; relv[10] = C[10]; relv[11] = C[11] - bz;
#pragma unroll
        for (int e = 0; e < 12; ++e)
            relBT[(size_t)(b * 12 + e) * K2 + j] = f2bf(relv[e]);
    }

    for (int idx = j; idx < KP - PF; idx += 64) {
        float val = (idx < NBETA) ? bet[idx] : (idx < NBETA + 2 ? 1.0f : 0.f);
        pfB[(size_t)b * KP + PF + idx] = f2bf(val);
    }

    for (int idx = j; idx < 12 * 8; idx += 64) {
        int e = idx >> 3, col = 24 + (idx & 7);
        float val = 0.f;
        if (col == 24) val = (e == 3) ? tr0 : (e == 7) ? tr1 : (e == 11) ? tr2 : 0.f;
        relBT[(size_t)(b * 12 + e) * K2 + col] = f2bf(val);
    }
}

// ---------------------------------------------------------------------------
// k_main v13 = R16's measured-best body (fp32 xls, lb(256,4)) + T1 XCD-
// bijective swizzle: 1-D grid, wg=(bid&7)*216+(bid>>3); vt=wg/16, btg=wg%16.
// Each XCD owns ~13.5 contiguous vt-slices -> pdT working set/XCD ~1.2 MB
// (fits 4 MB L2 with pfB+relBT) -> A-loads become L2 hits.
// ---------------------------------------------------------------------------
__global__ __launch_bounds__(256, 4) void k_main(
    const unsigned short* __restrict__ pdT,    // (V3PAD, KP) interleaved
    const unsigned short* __restrict__ pfB,    // (BB, KP)
    const unsigned short* __restrict__ lbswB,  // (VPAD, K2)
    const unsigned short* __restrict__ relBT,  // (BB*12, K2)
    float* __restrict__ verts)                 // (B,V,3)
{
    int bid = blockIdx.x;                     // 0..1727
    int wg  = (bid & 7) * (NWG / 8) + (bid >> 3);   // bijective (1728 % 8 == 0)
    int vt  = wg >> 4;          // 0..107  (contiguous range per XCD)
    int btg = wg & 15;          // 0..15
    int t   = threadIdx.x;
    int lane = t & 63;
    int w    = t >> 6;

    __shared__ float xls[4][16 * XSW];            // 13312 B
    __shared__ unsigned short Tls[4][16 * TSW];   // 25600 B

    int lr  = lane & 15;
    int hi2 = lane >> 4;
    int lk  = hi2 * 8;

    float* xw = &xls[w][0];
    unsigned short* Tw = &Tls[w][0];

    const unsigned short* pa = pdT + (size_t)(vt * M3 + w * 48 + lr) * KP + lk;
    s16x8 lf = *(const s16x8*)(lbswB + (size_t)(vt * VTB + w * 16 + lr) * K2 + lk);

    int vglob = vt * VTB + w * 16 + lr;
    bool vok = vglob < VV;

    for (int it = 0; it < NBT; ++it) {
        int b0 = (btg * NBT + it) * 16;

        // ---- GEMM1: D row = v3-sub (s*16+hi2*4+r), col = batch (lr) ----
        {
            f32x4 acc[3];
#pragma unroll
            for (int s = 0; s < 3; ++s) acc[s] = (f32x4){0.f,0.f,0.f,0.f};
            const unsigned short* pb = pfB + (size_t)(b0 + lr) * KP + lk;
#pragma unroll
            for (int ks = 0; ks < KP / 32; ++ks) {
                s16x8 bf = *(const s16x8*)(pb + ks * 32);
                s16x8 a0 = *(const s16x8*)(pa + ks * 32);
                s16x8 a1 = *(const s16x8*)(pa + (size_t)16 * KP + ks * 32);
                s16x8 a2 = *(const s16x8*)(pa + (size_t)32 * KP + ks * 32);
                acc[0] = __builtin_amdgcn_mfma_f32_16x16x32_bf16(a0, bf, acc[0], 0, 0, 0);
                acc[1] = __builtin_amdgcn_mfma_f32_16x16x32_bf16(a1, bf, acc[1], 0, 0, 0);
                acc[2] = __builtin_amdgcn_mfma_f32_16x16x32_bf16(a2, bf, acc[2], 0, 0, 0);
            }
#pragma unroll
            for (int s = 0; s < 3; ++s)
                *(f32x4*)&xw[lr * XSW + s * 16 + hi2 * 4] = acc[s];
        }

        // ---- GEMM2: T[be][vert] -> Tw[vert=lr][be] (per-wave, aligned) ----
#pragma unroll
        for (int mt = 0; mt < 12; ++mt) {
            s16x8 rf = *(const s16x8*)(relBT +
                (size_t)(b0 * 12 + mt * 16 + lr) * K2 + lk);
            f32x4 a2v = {0.f,0.f,0.f,0.f};
            a2v = __builtin_amdgcn_mfma_f32_16x16x32_bf16(rf, lf, a2v, 0, 0, 0);
            union { s16x4 v4; unsigned short u[4]; } pk;
#pragma unroll
            for (int r = 0; r < 4; ++r) pk.u[r] = f2bf(a2v[r]);
            *(s16x4*)&Tw[lr * TSW + mt * 16 + hi2 * 4] = pk.v4;
        }

        // ---- epilogue: vertex w*16+lr, batches hi2+4q ----
        if (vok) {
#pragma unroll
            for (int q = 0; q < 4; ++q) {
                int bl = hi2 + 4 * q;

                const float* xp = &xw[bl * XSW + 3 * lr];
                float x0 = xp[0], x1 = xp[1], x2 = xp[2];

                const unsigned short* tp = Tw + lr * TSW + bl * 12;
                uint2 dA = *(const uint2*)tp;
                uint2 dB = *(const uint2*)(tp + 4);
                uint2 dC = *(const uint2*)(tp + 8);
                float T0  = __uint_as_float(dA.x << 16);
                float T1  = __uint_as_float(dA.x & 0xffff0000u);
                float T2  = __uint_as_float(dA.y << 16);
                float T3  = __uint_as_float(dA.y & 0xffff0000u);
                float T4  = __uint_as_float(dB.x << 16);
                float T5  = __uint_as_float(dB.x & 0xffff0000u);
                float T6  = __uint_as_float(dB.y << 16);
                float T7  = __uint_as_float(dB.y & 0xffff0000u);
                float T8  = __uint_as_float(dC.x << 16);
                float T9  = __uint_as_float(dC.x & 0xffff0000u);
                float T10 = __uint_as_float(dC.y << 16);
                float T11 = __uint_as_float(dC.y & 0xffff0000u);

                float o0 = T0 * x0 + T1 * x1 + T2  * x2 + T3;
                float o1 = T4 * x0 + T5 * x1 + T6  * x2 + T7;
                float o2 = T8 * x0 + T9 * x1 + T10 * x2 + T11;

                float* o = verts + ((size_t)(b0 + bl) * VV + vglob) * 3;
                o[0] = o0; o[1] = o1; o[2] = o2;
            }
        }
    }
}

extern "C" void kernel_launch(void* const* d_in, const int* in_sizes, int n_in,
                              void* d_out, int out_size, void* d_ws, size_t ws_size,
                              hipStream_t stream) {
    const float* transl = (const float*)d_in[0];
    const float* orient = (const float*)d_in[1];
    const float* betas  = (const float*)d_in[2];
    const float* bpose  = (const float*)d_in[3];
    const float* vtemp  = (const float*)d_in[4];
    const float* sdirs  = (const float*)d_in[5];
    const float* pdirs  = (const float*)d_in[6];
    const float* jreg   = (const float*)d_in[7];
    const float* lbsw   = (const float*)d_in[8];

    float* out = (float*)d_out;
    float* verts_out  = out;
    float* joints_out = out + (size_t)BB * VV * 3;

    float* ws    = (float*)d_ws;
    float* jpart = ws;                                   // 24*8*33 = 6336 f
    unsigned short* pfB   = (unsigned short*)(ws + 6336);      // B*KP
    unsigned short* pdT   = pfB + (size_t)BB * KP;             // V3PAD*KP
    unsigned short* lbswB = pdT + (size_t)V3PAD * KP;          // VPAD*K2
    unsigned short* relBT = lbswB + (size_t)VPAD * K2;         // B*12*K2

    k_prep_all<<<NBLK_A + NBLK_B + NBLK_C, 256, 0, stream>>>(
        pdirs, sdirs, vtemp, lbsw, jreg, pdT, lbswB, jpart);
    k_batch<<<BB, 64, 0, stream>>>(transl, orient, betas, bpose,
                                   jpart, pfB, relBT, joints_out);
    k_main<<<NWG, 256, 0, stream>>>(pdT, pfB, lbswB, relBT, verts_out);
}

// Round 20
// 86.418 us; speedup vs baseline: 1.4131x; 1.1513x over previous
//
#include <hip/hip_runtime.h>

#define BB 1024
#define VV 6890
#define NJ 24
#define NBETA 10
#define PF 207            // (J-1)*9
#define V3 (VV*3)         // 20670
#define KP 224            // GEMM1 K: 207 pose + 10 shape + 2 vtemp(hi/lo) + 5 zero
#define VTB 64            // vertices per block tile in k_main
#define M3 (VTB*3)        // 192 v3-rows per tile
#define NVT ((VV + VTB - 1) / VTB)   // 108
#define V3PAD (NVT * VTB * 3)        // 20736 rows in pdT (row = v*3+c, interleaved)
#define VPAD (NVT * VTB)             // 6912
#define K2 32             // GEMM2 K: 24 joints + 1 transl-one + 7 zero
#define NCH 8             // jreg chunks
#define CHV 862           // ceil(VV/NCH)
#define NBLK_A (NVT * 4)             // 432: (v-block, k-quarter)
#define NBLK_B (VPAD / 256)          // 27
#define NBLK_C (NJ * NCH)            // 192
#define NBT 4             // batch-tiles per k_main block
#define XSW 52            // xls per-wave stride (dwords): [batch][v3local]
#define TSW 200           // Tls per-wave stride (u16): 400B, 8-B aligned

typedef float f32x4 __attribute__((ext_vector_type(4)));
typedef short s16x8 __attribute__((ext_vector_type(8)));
typedef short s16x4 __attribute__((ext_vector_type(4)));

__device__ __constant__ int kParents[NJ] = {-1,0,0,0,1,2,3,4,5,6,7,8,9,9,9,12,13,14,16,17,18,19,20,21};
// tree depth level of each joint (root = 0)
__device__ __constant__ int kLevel[NJ]   = {0,1,1,1,2,2,2,3,3,3,4,4,4,4,4,5,5,5,6,6,7,7,8,8};

__device__ __forceinline__ unsigned short f2bf(float x) {
    unsigned int u = __float_as_uint(x);
    unsigned int r = (u + 0x7fffu + ((u >> 16) & 1u)) >> 16;
    return (unsigned short)r;
}
__device__ __forceinline__ float bf2f(unsigned short h) {
    return __uint_as_float((unsigned int)h << 16);
}

// ---------------------------------------------------------------------------
// k_prep_all: A = pdT interleaved transpose, B = lbswB, C = jreg partials.
// ---------------------------------------------------------------------------
__global__ __launch_bounds__(256) void k_prep_all(
    const float* __restrict__ pdirs,     // (207, V3)
    const float* __restrict__ sdirs,     // (V3, 10)
    const float* __restrict__ vtemp,     // (V3)
    const float* __restrict__ lbsw,      // (V, 24)
    const float* __restrict__ Jreg,      // (24, V)
    unsigned short* __restrict__ pdT,    // (V3PAD, KP) interleaved
    unsigned short* __restrict__ lbswB,  // (VPAD, K2)
    float* __restrict__ jpart)           // (24, NCH, 33)
{
    int bid = blockIdx.x;
    int t = threadIdx.x;

    if (bid < NBLK_A) {
        int vb = bid >> 2;              // v-block 0..107
        int kq = bid & 3;               // k-quarter 0..3
        int kc0 = kq * 56;
        int v0 = vb * 64;
        __shared__ unsigned short tileA[3][56][65];   // 21840 B

        int ksub = t >> 6;              // 0..3
        int vo   = t & 63;
        int v    = v0 + vo;
        bool valid = v < VV;
        int v3b  = v * 3;
#pragma unroll
        for (int i = 0; i < 14; ++i) {
            int kl = ksub * 14 + i;     // 0..55
            int k  = kc0 + kl;
            float c0 = 0.f, c1 = 0.f, c2 = 0.f;
            if (valid) {
                if (k < PF) {
                    const float* p = pdirs + (size_t)k * V3 + v3b;
                    c0 = p[0]; c1 = p[1]; c2 = p[2];
                } else if (k < PF + NBETA) {
                    int l = k - PF;
                    c0 = sdirs[(size_t)(v3b + 0) * NBETA + l];
                    c1 = sdirs[(size_t)(v3b + 1) * NBETA + l];
                    c2 = sdirs[(size_t)(v3b + 2) * NBETA + l];
                } else if (k == PF + NBETA) {
                    c0 = vtemp[v3b]; c1 = vtemp[v3b + 1]; c2 = vtemp[v3b + 2];
                } else if (k == PF + NBETA + 1) {
                    float x0 = vtemp[v3b], x1 = vtemp[v3b + 1], x2 = vtemp[v3b + 2];
                    c0 = x0 - bf2f(f2bf(x0));
                    c1 = x1 - bf2f(f2bf(x1));
                    c2 = x2 - bf2f(f2bf(x2));
                }
            }
            tileA[0][kl][vo] = f2bf(c0);
            tileA[1][kl][vo] = f2bf(c1);
            tileA[2][kl][vo] = f2bf(c2);
        }
        __syncthreads();

        int vo2 = t >> 2;               // 0..63
        int sub = t & 3;
#pragma unroll
        for (int c = 0; c < 3; ++c) {
#pragma unroll
            for (int j = 0; j < 2; ++j) {
                int ch = sub + 4 * j;   // 0..7, need 0..6
                if (ch < 7) {
                    union { s16x8 v8; unsigned short u[8]; } pk;
#pragma unroll
                    for (int i = 0; i < 8; ++i) pk.u[i] = tileA[c][ch * 8 + i][vo2];
                    *(s16x8*)(pdT + (size_t)((v0 + vo2) * 3 + c) * KP
                                   + kc0 + ch * 8) = pk.v8;
                }
            }
        }
    } else if (bid < NBLK_A + NBLK_B) {
        int v = (bid - NBLK_A) * 256 + t;
        bool valid = v < VV;
        unsigned short* o = lbswB + (size_t)v * K2;
        union { s16x8 v8; unsigned short u[8]; } pk;
#pragma unroll
        for (int g = 0; g < 3; ++g) {
#pragma unroll
            for (int i = 0; i < 8; ++i)
                pk.u[i] = valid ? f2bf(lbsw[(size_t)v * NJ + g * 8 + i]) : (unsigned short)0;
            *(s16x8*)(o + g * 8) = pk.v8;
        }
        pk.u[0] = 0x3F80;               // col 24 = 1.0 (transl K-column)
#pragma unroll
        for (int i = 1; i < 8; ++i) pk.u[i] = 0;
        *(s16x8*)(o + 24) = pk.v8;
    } else {
        int idx = bid - NBLK_A - NBLK_B;
        int j  = idx / NCH;
        int ch = idx % NCH;
        int v0 = ch * CHV;
        int vend = min(VV, v0 + CHV);

        float acc[33];
#pragma unroll
        for (int i = 0; i < 33; ++i) acc[i] = 0.f;

        for (int v = v0 + t; v < vend; v += 256) {
            float w = Jreg[(size_t)j * VV + v];
            const float* sv = sdirs + (size_t)v * 30;
            float sd[30];
#pragma unroll
            for (int i = 0; i < 30; i += 2) {
                float2 x2 = *(const float2*)(sv + i);
                sd[i] = x2.x; sd[i + 1] = x2.y;
            }
#pragma unroll
            for (int c = 0; c < 3; ++c) {
                acc[30 + c] += w * vtemp[v * 3 + c];
#pragma unroll
                for (int l = 0; l < NBETA; ++l)
                    acc[c * NBETA + l] += w * sd[c * NBETA + l];
            }
        }
#pragma unroll
        for (int i = 0; i < 33; ++i) {
            float x = acc[i];
            for (int off = 32; off > 0; off >>= 1) x += __shfl_down(x, off);
            acc[i] = x;
        }
        __shared__ float sred[33][4];
        int wave = t >> 6, lane = t & 63;
        if (lane == 0) {
#pragma unroll
            for (int i = 0; i < 33; ++i) sred[i][wave] = acc[i];
        }
        __syncthreads();
        if (t == 0) {
#pragma unroll
            for (int i = 0; i < 33; ++i)
                jpart[(size_t)(j * NCH + ch) * 33 + i] =
                    sred[i][0] + sred[i][1] + sred[i][2] + sred[i][3];
        }
    }
}

// ---------------------------------------------------------------------------
// k_batch v2: one wave per batch, shfl chain.
// ---------------------------------------------------------------------------
__global__ __launch_bounds__(64) void k_batch(
    const float* __restrict__ transl,
    const float* __restrict__ orient,
    const float* __restrict__ betas,
    const float* __restrict__ bpose,
    const float* __restrict__ jpart,     // (24, NCH, 33)
    unsigned short* __restrict__ pfB,    // (B, KP)
    unsigned short* __restrict__ relBT,  // (B*12, K2)
    float* __restrict__ joints_out)      // (B, 24, 3)
{
    int b = blockIdx.x;
    int j = threadIdx.x;                 // lane; joints on 0..23

    __shared__ float sJ[NJ * 33];
    for (int idx = j; idx < NJ * 33; idx += 64) {
        int jj = idx / 33, i = idx % 33;
        float s = 0.f;
#pragma unroll
        for (int c = 0; c < NCH; ++c) s += jpart[(size_t)(jj * NCH + c) * 33 + i];
        sJ[idx] = s;
    }
    __syncthreads();

    float tr0 = transl[b * 3 + 0], tr1 = transl[b * 3 + 1], tr2 = transl[b * 3 + 2];

    float bet[NBETA];
#pragma unroll
    for (int l = 0; l < NBETA; ++l) bet[l] = betas[b * NBETA + l];

    bool act = j < NJ;
    int p   = (act && j > 0) ? kParents[j] : 0;
    int lvl = act ? kLevel[j] : 0;

    float jxx = 0.f, jyy = 0.f, jzz = 0.f;
    if (act) {
        jxx = sJ[j * 33 + 30]; jyy = sJ[j * 33 + 31]; jzz = sJ[j * 33 + 32];
#pragma unroll
        for (int l = 0; l < NBETA; ++l) {
            jxx += sJ[j * 33 + l]      * bet[l];
            jyy += sJ[j * 33 + 10 + l] * bet[l];
            jzz += sJ[j * 33 + 20 + l] * bet[l];
        }
    }
    float pxx = __shfl(jxx, p), pyy = __shfl(jyy, p), pzz = __shfl(jzz, p);

    float rx = 0.f, ry = 0.f, rz = 0.f;
    if (act) {
        if (j == 0) {
            rx = orient[b * 3 + 0]; ry = orient[b * 3 + 1]; rz = orient[b * 3 + 2];
        } else {
            rx = bpose[b * 69 + (j - 1) * 3 + 0];
            ry = bpose[b * 69 + (j - 1) * 3 + 1];
            rz = bpose[b * 69 + (j - 1) * 3 + 2];
        }
    }
    float ax = rx + 1e-8f, ay = ry + 1e-8f, az = rz + 1e-8f;
    float angle = sqrtf(ax * ax + ay * ay + az * az);
    float inv = 1.f / angle;
    float kx = rx * inv, ky = ry * inv, kz = rz * inv;
    float s = sinf(angle), c = cosf(angle), omc = 1.f - c;
    float R[9];
    R[0] = 1.f - omc * (ky * ky + kz * kz);
    R[1] = -s * kz + omc * (kx * ky);
    R[2] =  s * ky + omc * (kx * kz);
    R[3] =  s * kz + omc * (kx * ky);
    R[4] = 1.f - omc * (kx * kx + kz * kz);
    R[5] = -s * kx + omc * (ky * kz);
    R[6] = -s * ky + omc * (kx * kz);
    R[7] =  s * kx + omc * (ky * kz);
    R[8] = 1.f - omc * (kx * kx + ky * ky);

    if (act && j > 0) {
#pragma unroll
        for (int e = 0; e < 9; ++e) {
            float val = R[e] - ((e == 0 || e == 4 || e == 8) ? 1.f : 0.f);
            pfB[(size_t)b * KP + (j - 1) * 9 + e] = f2bf(val);
        }
    }

    float tx, ty, tz;
    if (j == 0) { tx = jxx; ty = jyy; tz = jzz; }
    else        { tx = jxx - pxx; ty = jyy - pyy; tz = jzz - pzz; }

    float C[12];
    C[0] = R[0]; C[1] = R[1]; C[2]  = R[2]; C[3]  = tx;
    C[4] = R[3]; C[5] = R[4]; C[6]  = R[5]; C[7]  = ty;
    C[8] = R[6]; C[9] = R[7]; C[10] = R[8]; C[11] = tz;

#pragma unroll
    for (int L = 1; L <= 8; ++L) {
        float P[12];
#pragma unroll
        for (int e = 0; e < 12; ++e) P[e] = __shfl(C[e], p);
        if (lvl == L) {
            float N[12];
#pragma unroll
            for (int r = 0; r < 3; ++r) {
#pragma unroll
                for (int cc = 0; cc < 3; ++cc)
                    N[r * 4 + cc] = P[r * 4 + 0] * R[0 * 3 + cc] +
                                    P[r * 4 + 1] * R[1 * 3 + cc] +
                                    P[r * 4 + 2] * R[2 * 3 + cc];
                N[r * 4 + 3] = P[r * 4 + 0] * tx + P[r * 4 + 1] * ty +
                               P[r * 4 + 2] * tz + P[r * 4 + 3];
            }
#pragma unroll
            for (int e = 0; e < 12; ++e) C[e] = N[e];
        }
    }

    if (act) {
        joints_out[(b * NJ + j) * 3 + 0] = C[3]  + tr0;
        joints_out[(b * NJ + j) * 3 + 1] = C[7]  + tr1;
        joints_out[(b * NJ + j) * 3 + 2] = C[11] + tr2;

        float bx = C[0] * jxx + C[1] * jyy + C[2]  * jzz;
        float by = C[4] * jxx + C[5] * jyy + C[6]  * jzz;
        float bz = C[8] * jxx + C[9] * jyy + C[10] * jzz;
        float relv[12];
        relv[0] = C[0]; relv[1] = C[1]; relv[2]  = C[2];  relv[3]  = C[3]  - bx;
        relv[4] = C[4]; relv[5] = C[5]; relv[6]  = C[6];  relv[7]  = C[7]  - by;
        relv[8] = C[8]; relv[9] = C[9]; relv[10] = C[10]; relv[11] = C[11] - bz;
#pragma unroll
        for (int e = 0; e < 12; ++e)
            relBT[(size_t)(b * 12 + e) * K2 + j] = f2bf(relv[e]);
    }

    for (int idx = j; idx < KP - PF; idx += 64) {
        float val = (idx < NBETA) ? bet[idx] : (idx < NBETA + 2 ? 1.0f : 0.f);
        pfB[(size_t)b * KP + PF + idx] = f2bf(val);
    }

    for (int idx = j; idx < 12 * 8; idx += 64) {
        int e = idx >> 3, col = 24 + (idx & 7);
        float val = 0.f;
        if (col == 24) val = (e == 3) ? tr0 : (e == 7) ? tr1 : (e == 11) ? tr2 : 0.f;
        relBT[(size_t)(b * 12 + e) * K2 + col] = f2bf(val);
    }
}

// ---------------------------------------------------------------------------
// k_main (R16's measured-best: per-batch-tile GEMM1, wave-private LDS,
// barrier-free, default 2-D dispatch order)
// ---------------------------------------------------------------------------
__global__ __launch_bounds__(256, 4) void k_main(
    const unsigned short* __restrict__ pdT,    // (V3PAD, KP) interleaved
    const unsigned short* __restrict__ pfB,    // (BB, KP)
    const unsigned short* __restrict__ lbswB,  // (VPAD, K2)
    const unsigned short* __restrict__ relBT,  // (BB*12, K2)
    float* __restrict__ verts)                 // (B,V,3)
{
    int btg = blockIdx.x;           // 0..15 (4 batch-tiles each)
    int vt  = blockIdx.y;           // 0..107
    int t   = threadIdx.x;
    int lane = t & 63;
    int w    = t >> 6;

    __shared__ float xls[4][16 * XSW];            // 13312 B
    __shared__ unsigned short Tls[4][16 * TSW];   // 25600 B

    int lr  = lane & 15;
    int hi2 = lane >> 4;
    int lk  = hi2 * 8;

    float* xw = &xls[w][0];
    unsigned short* Tw = &Tls[w][0];

    const unsigned short* pa = pdT + (size_t)(vt * M3 + w * 48 + lr) * KP + lk;
    s16x8 lf = *(const s16x8*)(lbswB + (size_t)(vt * VTB + w * 16 + lr) * K2 + lk);

    int vglob = vt * VTB + w * 16 + lr;
    bool vok = vglob < VV;

    for (int it = 0; it < NBT; ++it) {
        int b0 = (btg * NBT + it) * 16;

        // ---- GEMM1: D row = v3-sub (s*16+hi2*4+r), col = batch (lr) ----
        {
            f32x4 acc[3];
#pragma unroll
            for (int s = 0; s < 3; ++s) acc[s] = (f32x4){0.f,0.f,0.f,0.f};
            const unsigned short* pb = pfB + (size_t)(b0 + lr) * KP + lk;
#pragma unroll
            for (int ks = 0; ks < KP / 32; ++ks) {
                s16x8 bf = *(const s16x8*)(pb + ks * 32);
                s16x8 a0 = *(const s16x8*)(pa + ks * 32);
                s16x8 a1 = *(const s16x8*)(pa + (size_t)16 * KP + ks * 32);
                s16x8 a2 = *(const s16x8*)(pa + (size_t)32 * KP + ks * 32);
                acc[0] = __builtin_amdgcn_mfma_f32_16x16x32_bf16(a0, bf, acc[0], 0, 0, 0);
                acc[1] = __builtin_amdgcn_mfma_f32_16x16x32_bf16(a1, bf, acc[1], 0, 0, 0);
                acc[2] = __builtin_amdgcn_mfma_f32_16x16x32_bf16(a2, bf, acc[2], 0, 0, 0);
            }
#pragma unroll
            for (int s = 0; s < 3; ++s)
                *(f32x4*)&xw[lr * XSW + s * 16 + hi2 * 4] = acc[s];
        }

        // ---- GEMM2: T[be][vert] -> Tw[vert=lr][be] (per-wave, aligned) ----
#pragma unroll
        for (int mt = 0; mt < 12; ++mt) {
            s16x8 rf = *(const s16x8*)(relBT +
                (size_t)(b0 * 12 + mt * 16 + lr) * K2 + lk);
            f32x4 a2v = {0.f,0.f,0.f,0.f};
            a2v = __builtin_amdgcn_mfma_f32_16x16x32_bf16(rf, lf, a2v, 0, 0, 0);
            union { s16x4 v4; unsigned short u[4]; } pk;
#pragma unroll
            for (int r = 0; r < 4; ++r) pk.u[r] = f2bf(a2v[r]);
            *(s16x4*)&Tw[lr * TSW + mt * 16 + hi2 * 4] = pk.v4;
        }

        // ---- epilogue: vertex w*16+lr, batches hi2+4q ----
        if (vok) {
#pragma unroll
            for (int q = 0; q < 4; ++q) {
                int bl = hi2 + 4 * q;

                const float* xp = &xw[bl * XSW + 3 * lr];
                float x0 = xp[0], x1 = xp[1], x2 = xp[2];

                const unsigned short* tp = Tw + lr * TSW + bl * 12;
                uint2 dA = *(const uint2*)tp;
                uint2 dB = *(const uint2*)(tp + 4);
                uint2 dC = *(const uint2*)(tp + 8);
                float T0  = __uint_as_float(dA.x << 16);
                float T1  = __uint_as_float(dA.x & 0xffff0000u);
                float T2  = __uint_as_float(dA.y << 16);
                float T3  = __uint_as_float(dA.y & 0xffff0000u);
                float T4  = __uint_as_float(dB.x << 16);
                float T5  = __uint_as_float(dB.x & 0xffff0000u);
                float T6  = __uint_as_float(dB.y << 16);
                float T7  = __uint_as_float(dB.y & 0xffff0000u);
                float T8  = __uint_as_float(dC.x << 16);
                float T9  = __uint_as_float(dC.x & 0xffff0000u);
                float T10 = __uint_as_float(dC.y << 16);
                float T11 = __uint_as_float(dC.y & 0xffff0000u);

                float o0 = T0 * x0 + T1 * x1 + T2  * x2 + T3;
                float o1 = T4 * x0 + T5 * x1 + T6  * x2 + T7;
                float o2 = T8 * x0 + T9 * x1 + T10 * x2 + T11;

                float* o = verts + ((size_t)(b0 + bl) * VV + vglob) * 3;
                o[0] = o0; o[1] = o1; o[2] = o2;
            }
        }
    }
}

extern "C" void kernel_launch(void* const* d_in, const int* in_sizes, int n_in,
                              void* d_out, int out_size, void* d_ws, size_t ws_size,
                              hipStream_t stream) {
    const float* transl = (const float*)d_in[0];
    const float* orient = (const float*)d_in[1];
    const float* betas  = (const float*)d_in[2];
    const float* bpose  = (const float*)d_in[3];
    const float* vtemp  = (const float*)d_in[4];
    const float* sdirs  = (const float*)d_in[5];
    const float* pdirs  = (const float*)d_in[6];
    const float* jreg   = (const float*)d_in[7];
    const float* lbsw   = (const float*)d_in[8];

    float* out = (float*)d_out;
    float* verts_out  = out;
    float* joints_out = out + (size_t)BB * VV * 3;

    float* ws    = (float*)d_ws;
    float* jpart = ws;                                   // 24*8*33 = 6336 f
    unsigned short* pfB   = (unsigned short*)(ws + 6336);      // B*KP
    unsigned short* pdT   = pfB + (size_t)BB * KP;             // V3PAD*KP
    unsigned short* lbswB = pdT + (size_t)V3PAD * KP;          // VPAD*K2
    unsigned short* relBT = lbswB + (size_t)VPAD * K2;         // B*12*K2

    k_prep_all<<<NBLK_A + NBLK_B + NBLK_C, 256, 0, stream>>>(
        pdirs, sdirs, vtemp, lbsw, jreg, pdT, lbswB, jpart);
    k_batch<<<BB, 64, 0, stream>>>(transl, orient, betas, bpose,
                                   jpart, pfB, relBT, joints_out);
    dim3 g(BB / 16 / NBT, NVT);
    k_main<<<g, 256, 0, stream>>>(pdT, pfB, lbswB, relBT, verts_out);
}